// Round 8
// baseline (260.665 us; speedup 1.0000x reference)
//
#include <hip/hip_runtime.h>
#include <math.h>

typedef _Float16 f16;
typedef __attribute__((ext_vector_type(2))) _Float16 f16x2;
typedef __attribute__((ext_vector_type(4))) _Float16 f16x4;
typedef __attribute__((ext_vector_type(8))) _Float16 f16x8;
typedef __attribute__((ext_vector_type(4))) float f32x4;

#define NBATCH 8
#define WSA_ELE 36864      // 32*1152 (w_off padded to 32 rows, k-major, frag-swizzled)
#define WSB_ELE 147456     // 128*1152 (w_def, k-major, frag-swizzled)
#define PREP_BLOCKS 720    // (WSA_ELE + WSB_ELE) / 256
// workspace byte offsets
#define OFF_WSB  73728
#define OFF_XT   368640
#define OFF_SCR  8757248   // scratch output for ablation variants (16 MB region)

__device__ __forceinline__ void gload_lds16(const f16* gsrc, f16* ldst) {
  // wave-uniform LDS base; HW adds lane*16
  __builtin_amdgcn_global_load_lds(
      (const __attribute__((address_space(1))) unsigned int*)gsrc,
      (__attribute__((address_space(3))) unsigned int*)ldst, 16, 0, 0);
}

// ---------------- merged prep (weights -> fp16 frag-swizzled) + transpose ----------------
__global__ __launch_bounds__(256) void prep_transpose_kernel(const float* __restrict__ w_off,
                                                             const float* __restrict__ w_def,
                                                             f16* __restrict__ wsA,
                                                             f16* __restrict__ wsB,
                                                             const float* __restrict__ x,
                                                             f16* __restrict__ xt) {
  __shared__ __align__(16) f16 s_t[128 * 68];   // pitch 68: 8B-aligned rows
  const int t = threadIdx.x;
  if (blockIdx.x < PREP_BLOCKS) {
    int i = blockIdx.x * 256 + t;
    if (i < WSA_ELE) {
      int j = i & 7, lane = (i >> 3) & 63, fm = i >> 9;
      int ch = fm >> 1, mt = fm & 1;
      int row = mt * 16 + (lane & 15);
      int kidx = ch * 32 + (lane >> 4) * 8 + j;
      int k = kidx >> 7, cc = kidx & 127;
      float v = (row < 27) ? w_off[row * 1152 + cc * 9 + k] : 0.0f;
      wsA[i] = (f16)v;
    } else {
      int e = i - WSA_ELE;
      int j = e & 7, lane = (e >> 3) & 63, fm = e >> 9;
      int ch = fm >> 3, mt = fm & 7;
      int row = mt * 16 + (lane & 15);
      int kidx = ch * 32 + (lane >> 4) * 8 + j;
      int k = kidx >> 7, cc = kidx & 127;
      wsB[e] = (f16)w_def[row * 1152 + cc * 9 + k];
    }
    return;
  }
  const int bid = blockIdx.x - PREP_BLOCKS;
  const int b = bid >> 6;
  const int pos0 = (bid & 63) << 6;
  const float* xb = x + ((size_t)b << 19);
  #pragma unroll
  for (int it = 0; it < 8; ++it) {
    int i = it * 256 + t;
    int c = i >> 4, p4 = (i & 15) << 2;
    float4 v = *(const float4*)&xb[c * 4096 + pos0 + p4];
    f16x4 h = {(f16)v.x, (f16)v.y, (f16)v.z, (f16)v.w};
    *(f16x4*)&s_t[c * 68 + p4] = h;
  }
  __syncthreads();
  f16* xtb = xt + ((size_t)b << 19);
  #pragma unroll
  for (int it = 0; it < 8; ++it) {
    int i = it * 256 + t;
    int p = i >> 5, c4 = (i & 31) << 2;
    f16x4 h = {s_t[(c4    ) * 68 + p],
               s_t[(c4 + 1) * 68 + p],
               s_t[(c4 + 2) * 68 + p],
               s_t[(c4 + 3) * 68 + p]};
    *(f16x4*)&xtb[(size_t)(pos0 + p) * 128 + c4] = h;
  }
}

// ---------------- fused DCN, templated for within-probe ablation ----------------
// MODE 0 = FULL (real output, identical to the 56.2us R5 kernel)
// MODE 1 = NOGATHER: corner loads replaced by uniform 4-line loads (scatter deleted)
// MODE 2 = NOSTAGE: in-loop global_load_lds deleted (stale A; scratch output)
// MODE 3 = NOBARRIER: per-chunk __syncthreads deleted (races; scratch output)
template<int MODE>
__global__ __launch_bounds__(256) void fused_dcn_kernel(const f16* __restrict__ xt,
                                                        const f16* __restrict__ wsA,
                                                        const f16* __restrict__ wsB,
                                                        const float* __restrict__ b_off,
                                                        const float* __restrict__ b_def,
                                                        float* __restrict__ out,
                                                        float* __restrict__ scratch) {
  __shared__ float  s_off[27 * 65];             // offset-conv row, pitch 65 (conflict-free)
  __shared__ uint4  s_ofs[576];                 // per-(k,px) corner byte-offsets
  __shared__ float4 s_wt[576];                  // per-(k,px) modulated weights
  __shared__ __align__(16) f16 s_a[2][4096];    // 2 x 8 KB A double-buffer
  const int t = threadIdx.x;
  const int b = blockIdx.x & 7, ho = blockIdx.x >> 3;   // XCD = batch
  const int lane = t & 63, wid = t >> 6;
  const int q = lane >> 4, li = lane & 15;
  const int px = (wid << 4) + li;
  const char* xtb = (const char*)xt + ((size_t)b << 20);

  // stage chunk 0 of A early; drains at the phase-1 barrier
  {
    const int seg = wid * 2;
    gload_lds16(wsB + seg * 512 + lane * 8,       &s_a[0][seg * 512]);
    gload_lds16(wsB + (seg + 1) * 512 + lane * 8, &s_a[0][(seg + 1) * 512]);
  }

  // ---- phase 1: offset conv, M=32 (27 live rows), fully unrolled im2col MFMA ----
  {
    f32x4 acc0 = {0.f, 0.f, 0.f, 0.f}, acc1 = {0.f, 0.f, 0.f, 0.f};
    #pragma unroll
    for (int k = 0; k < 9; ++k) {
      const int ky = k / 3, kx = k - ky * 3;
      const int y = ho + ky - 1;
      const int xx = px + kx - 1;
      const bool valid = ((unsigned)y < 64u) && ((unsigned)xx < 64u);
      const int pos = min(max(y, 0), 63) * 64 + min(max(xx, 0), 63);
      const int voff = pos * 256 + q * 16;   // bytes; +c4*64 as imm below
      #pragma unroll
      for (int c4 = 0; c4 < 4; ++c4) {
        union { uint4 u; f16x8 v; } bu;
        bu.u = *(const uint4*)(xtb + voff + c4 * 64);
        if (!valid) { bu.u.x = 0u; bu.u.y = 0u; bu.u.z = 0u; bu.u.w = 0u; }
        const int ch = k * 4 + c4;
        f16x8 a0 = *(const f16x8*)&wsA[(ch * 2    ) * 512 + lane * 8];
        f16x8 a1 = *(const f16x8*)&wsA[(ch * 2 + 1) * 512 + lane * 8];
        acc0 = __builtin_amdgcn_mfma_f32_16x16x32_f16(a0, bu.v, acc0, 0, 0, 0);
        acc1 = __builtin_amdgcn_mfma_f32_16x16x32_f16(a1, bu.v, acc1, 0, 0, 0);
      }
    }
    #pragma unroll
    for (int mt = 0; mt < 2; ++mt) {
      f32x4 a = mt ? acc1 : acc0;
      #pragma unroll
      for (int r = 0; r < 4; ++r) {
        int oc = mt * 16 + q * 4 + r;
        if (oc < 27) {
          float v = a[r] + b_off[oc];
          if (oc >= 18) v = 1.0f / (1.0f + __expf(-v));
          s_off[oc * 65 + px] = v;
        }
      }
    }
  }
  __syncthreads();   // offset row ready + chunk-0 A staging drained

  // ---- phase 2: bilinear table (ci-invariant corner offsets + premultiplied weights) ----
  for (int f = t; f < 576; f += 256) {
    int k = f >> 6, p = f & 63;
    int ky = k / 3, kx = k - ky * 3;
    float oy = s_off[(2 * k    ) * 65 + p];
    float ox = s_off[(2 * k + 1) * 65 + p];
    float m  = s_off[(18 + k   ) * 65 + p];
    float py  = oy + (float)(ho + ky - 1);
    float pxf = ox + (float)(p + kx - 1);
    float y0f = floorf(py), x0f = floorf(pxf);
    float wy = py - y0f, wx = pxf - x0f;
    int y0 = (int)y0f, x0 = (int)x0f;
    int y1 = y0 + 1, x1 = x0 + 1;
    bool y0v = (unsigned)y0 < 64u, y1v = (unsigned)y1 < 64u;
    bool x0v = (unsigned)x0 < 64u, x1v = (unsigned)x1 < 64u;
    int y0c = min(max(y0, 0), 63), y1c = min(max(y1, 0), 63);
    int x0c = min(max(x0, 0), 63), x1c = min(max(x1, 0), 63);
    uint4 o4;
    o4.x = (unsigned)((y0c * 64 + x0c) * 256);
    o4.y = (unsigned)((y0c * 64 + x1c) * 256);
    o4.z = (unsigned)((y1c * 64 + x0c) * 256);
    o4.w = (unsigned)((y1c * 64 + x1c) * 256);
    float4 w4;
    w4.x = (y0v && x0v) ? (1.f - wy) * (1.f - wx) * m : 0.f;
    w4.y = (y0v && x1v) ? (1.f - wy) * wx         * m : 0.f;
    w4.z = (y1v && x0v) ? wy         * (1.f - wx) * m : 0.f;
    w4.w = (y1v && x1v) ? wy         * wx         * m : 0.f;
    s_ofs[f] = o4;
    s_wt[f]  = w4;
  }
  __syncthreads();   // table ready

  // ---- phase 3: LDS-dbuf A + one-chunk-ahead register-prefetched gathers ----
  f32x4 acc[8];
  #pragma unroll
  for (int mt = 0; mt < 8; ++mt) acc[mt] = (f32x4){0.f, 0.f, 0.f, 0.f};

  union U4 { uint4 u; f16x2 h[4]; };
  U4 d0c, d1c, d2c, d3c;

  // prefetch chunk 0 gathers (k=0, c4=0)
  {
    const uint4 o4 = s_ofs[px];
    if constexpr (MODE == 1) {
      asm volatile("" :: "v"(o4.x), "v"(o4.y), "v"(o4.z), "v"(o4.w));
      const unsigned add = q * 16;
      d0c.u = *(const uint4*)(xtb + add);
      d1c.u = *(const uint4*)(xtb + 16384 + add);
      d2c.u = *(const uint4*)(xtb + 32768 + add);
      d3c.u = *(const uint4*)(xtb + 49152 + add);
    } else {
      d0c.u = *(const uint4*)(xtb + o4.x + q * 16);
      d1c.u = *(const uint4*)(xtb + o4.y + q * 16);
      d2c.u = *(const uint4*)(xtb + o4.z + q * 16);
      d3c.u = *(const uint4*)(xtb + o4.w + q * 16);
    }
  }

  #pragma unroll 1
  for (int ch = 0; ch < 36; ++ch) {
    const int k = ch >> 2;
    // stage A for next chunk into the other LDS buffer
    if (ch < 35) {
      if constexpr (MODE != 2) {
        const int nb = (ch + 1) & 1;
        const int seg = wid * 2;
        const f16* src = wsB + (ch + 1) * 4096;
        gload_lds16(src + seg * 512 + lane * 8,       &s_a[nb][seg * 512]);
        gload_lds16(src + (seg + 1) * 512 + lane * 8, &s_a[nb][(seg + 1) * 512]);
      }
    }
    // issue next chunk's gathers NOW (used a full iteration later)
    U4 d0n, d1n, d2n, d3n;
    if (ch < 35) {
      const int kn = (ch + 1) >> 2, c4n = (ch + 1) & 3;
      const uint4 o4n = s_ofs[kn * 64 + px];
      const unsigned add = q * 16 + c4n * 64;
      if constexpr (MODE == 1) {
        asm volatile("" :: "v"(o4n.x), "v"(o4n.y), "v"(o4n.z), "v"(o4n.w));
        d0n.u = *(const uint4*)(xtb + add);
        d1n.u = *(const uint4*)(xtb + 16384 + add);
        d2n.u = *(const uint4*)(xtb + 32768 + add);
        d3n.u = *(const uint4*)(xtb + 49152 + add);
      } else {
        d0n.u = *(const uint4*)(xtb + o4n.x + add);
        d1n.u = *(const uint4*)(xtb + o4n.y + add);
        d2n.u = *(const uint4*)(xtb + o4n.z + add);
        d3n.u = *(const uint4*)(xtb + o4n.w + add);
      }
    }
    // pack current chunk's B fragment
    const float4 w4 = s_wt[k * 64 + px];
    const f16 h0 = (f16)w4.x, h1 = (f16)w4.y, h2 = (f16)w4.z, h3 = (f16)w4.w;
    const f16x2 wp0 = {h0, h0}, wp1 = {h1, h1}, wp2 = {h2, h2}, wp3 = {h3, h3};
    union { f16x2 h[4]; f16x8 v; } bf;
    #pragma unroll
    for (int i = 0; i < 4; ++i) {
      f16x2 s = d0c.h[i] * wp0;
      s = s + d1c.h[i] * wp1;
      s = s + d2c.h[i] * wp2;
      s = s + d3c.h[i] * wp3;
      bf.h[i] = s;
    }
    const f16* ab = &s_a[ch & 1][0];
    #pragma unroll
    for (int mt = 0; mt < 8; ++mt) {
      f16x8 a = *(const f16x8*)&ab[(mt * 64 + lane) * 8];
      acc[mt] = __builtin_amdgcn_mfma_f32_16x16x32_f16(a, bf.v, acc[mt], 0, 0, 0);
    }
    if constexpr (MODE != 3) {
      __syncthreads();   // drain staging (+in-flight gathers land under MFMA work)
    }
    if (ch < 35) { d0c = d0n; d1c = d1n; d2c = d2n; d3c = d3n; }
  }

  float* obase = (MODE == 0) ? out : scratch;
  float* o = obase + (size_t)b * 128 * 4096 + ho * 64 + px;
  #pragma unroll
  for (int mt = 0; mt < 8; ++mt) {
    #pragma unroll
    for (int r = 0; r < 4; ++r) {
      int oc = mt * 16 + q * 4 + r;
      o[oc * 4096] = acc[mt][r] + b_def[oc];
    }
  }
}

extern "C" void kernel_launch(void* const* d_in, const int* in_sizes, int n_in,
                              void* d_out, int out_size, void* d_ws, size_t ws_size,
                              hipStream_t stream) {
  const float* x     = (const float*)d_in[0];
  const float* w_off = (const float*)d_in[1];
  const float* b_off = (const float*)d_in[2];
  const float* w_def = (const float*)d_in[3];
  const float* b_def = (const float*)d_in[4];
  float* out = (float*)d_out;

  f16*   wsA = (f16*)d_ws;
  f16*   wsB = (f16*)((char*)d_ws + OFF_WSB);
  f16*   xt  = (f16*)((char*)d_ws + OFF_XT);
  float* scr = (float*)((char*)d_ws + OFF_SCR);

  prep_transpose_kernel<<<dim3(PREP_BLOCKS + NBATCH * 64), dim3(256), 0, stream>>>(
      w_off, w_def, wsA, wsB, x, xt);
  // real result (reproduces R5)
  fused_dcn_kernel<0><<<dim3(NBATCH * 64), dim3(256), 0, stream>>>(
      xt, wsA, wsB, b_off, b_def, out, scr);
  // ablation probes (scratch output; deltas read from rocprof top-5 + dur sum)
  fused_dcn_kernel<1><<<dim3(NBATCH * 64), dim3(256), 0, stream>>>(
      xt, wsA, wsB, b_off, b_def, out, scr);
  fused_dcn_kernel<2><<<dim3(NBATCH * 64), dim3(256), 0, stream>>>(
      xt, wsA, wsB, b_off, b_def, out, scr);
  fused_dcn_kernel<3><<<dim3(NBATCH * 64), dim3(256), 0, stream>>>(
      xt, wsA, wsB, b_off, b_def, out, scr);
}

// Round 10
// 130.755 us; speedup vs baseline: 1.9935x; 1.9935x over previous
//
#include <hip/hip_runtime.h>
#include <math.h>

typedef _Float16 f16;
typedef __attribute__((ext_vector_type(2))) _Float16 f16x2;
typedef __attribute__((ext_vector_type(4))) _Float16 f16x4;
typedef __attribute__((ext_vector_type(8))) _Float16 f16x8;
typedef __attribute__((ext_vector_type(4))) float f32x4;

#define NBATCH 8
#define WSA_ELE 36864      // 32*1152 (w_off padded to 32 rows, k-major, frag-swizzled)
#define WSB_ELE 147456     // 128*1152 (w_def, k-major, frag-swizzled)
#define PREP_BLOCKS 720    // (WSA_ELE + WSB_ELE) / 256
// workspace byte offsets
#define OFF_WSB  73728
#define OFF_XT   368640

__device__ __forceinline__ void gload_lds16(const f16* gsrc, f16* ldst) {
  // global source is PER-LANE (must include lane*8 f16); LDS dest is
  // wave-uniform base, HW adds lane*16 bytes.
  __builtin_amdgcn_global_load_lds(
      (const __attribute__((address_space(1))) unsigned int*)gsrc,
      (__attribute__((address_space(3))) unsigned int*)ldst, 16, 0, 0);
}

// ---------------- merged prep (weights -> fp16 frag-swizzled) + transpose ----------------
__global__ __launch_bounds__(256) void prep_transpose_kernel(const float* __restrict__ w_off,
                                                             const float* __restrict__ w_def,
                                                             f16* __restrict__ wsA,
                                                             f16* __restrict__ wsB,
                                                             const float* __restrict__ x,
                                                             f16* __restrict__ xt) {
  __shared__ __align__(16) f16 s_t[128 * 68];   // pitch 68: 8B-aligned rows
  const int t = threadIdx.x;
  if (blockIdx.x < PREP_BLOCKS) {
    int i = blockIdx.x * 256 + t;
    if (i < WSA_ELE) {
      int j = i & 7, lane = (i >> 3) & 63, fm = i >> 9;
      int ch = fm >> 1, mt = fm & 1;
      int row = mt * 16 + (lane & 15);
      int kidx = ch * 32 + (lane >> 4) * 8 + j;
      int k = kidx >> 7, cc = kidx & 127;
      float v = (row < 27) ? w_off[row * 1152 + cc * 9 + k] : 0.0f;
      wsA[i] = (f16)v;
    } else {
      int e = i - WSA_ELE;
      int j = e & 7, lane = (e >> 3) & 63, fm = e >> 9;
      int ch = fm >> 3, mt = fm & 7;
      int row = mt * 16 + (lane & 15);
      int kidx = ch * 32 + (lane >> 4) * 8 + j;
      int k = kidx >> 7, cc = kidx & 127;
      wsB[e] = (f16)w_def[row * 1152 + cc * 9 + k];
    }
    return;
  }
  const int bid = blockIdx.x - PREP_BLOCKS;
  const int b = bid >> 6;
  const int pos0 = (bid & 63) << 6;
  const float* xb = x + ((size_t)b << 19);
  #pragma unroll
  for (int it = 0; it < 8; ++it) {
    int i = it * 256 + t;
    int c = i >> 4, p4 = (i & 15) << 2;
    float4 v = *(const float4*)&xb[c * 4096 + pos0 + p4];
    f16x4 h = {(f16)v.x, (f16)v.y, (f16)v.z, (f16)v.w};
    *(f16x4*)&s_t[c * 68 + p4] = h;
  }
  __syncthreads();
  f16* xtb = xt + ((size_t)b << 19);
  #pragma unroll
  for (int it = 0; it < 8; ++it) {
    int i = it * 256 + t;
    int p = i >> 5, c4 = (i & 31) << 2;
    f16x4 h = {s_t[(c4    ) * 68 + p],
               s_t[(c4 + 1) * 68 + p],
               s_t[(c4 + 2) * 68 + p],
               s_t[(c4 + 3) * 68 + p]};
    *(f16x4*)&xtb[(size_t)(pos0 + p) * 128 + c4] = h;
  }
}

// ---------------- fused DCN: half-tap pipelined schedule ----------------
// 18 iterations, one half-tap (2 K=32 chunks) each. Per iter:
//   vmcnt(12) | s_barrier | issue G(h+1) 8 gathers + S(h+2) 4 gload_lds | compute(h)
// Steady state per wave: before the wait, outstanding = G(h)8+S(h+1)4 (iter h-1)
// + S(h)4 (iter h-2) = 16; vmcnt(12) drains exactly S(h) -- just in time for
// compute(h)'s ds_reads of buf[h%3]. Counted waits never hit 0 in the loop.
// Issue-after-barrier makes the 3-deep buffer race-free (every write is
// barrier-separated from the last read of that buffer).
__global__ __launch_bounds__(256, 2) void fused_dcn_kernel(const f16* __restrict__ xt,
                                                           const f16* __restrict__ wsA,
                                                           const f16* __restrict__ wsB,
                                                           const float* __restrict__ b_off,
                                                           const float* __restrict__ b_def,
                                                           float* __restrict__ out) {
  __shared__ float  s_off[27 * 65];             // offset-conv row, pitch 65 (conflict-free)
  __shared__ uint4  s_ofs[576];                 // per-(k,px) corner byte-offsets
  __shared__ float4 s_wt[576];                  // per-(k,px) modulated weights
  __shared__ __align__(16) f16 s_a[3 * 8192];   // 3 x 16 KB half-tap triple buffer
  const int t = threadIdx.x;
  const int b = blockIdx.x & 7, ho = blockIdx.x >> 3;   // XCD = batch
  const int lane = t & 63, wid = t >> 6;
  const int q = lane >> 4, li = lane & 15;
  const int px = (wid << 4) + li;
  const char* xtb = (const char*)xt + ((size_t)b << 20);

  // pre-stage half-taps 0 and 1 (drained by the phase-1 __syncthreads)
  #pragma unroll
  for (int j = 0; j < 4; ++j) {
    gload_lds16(wsB +        (wid * 4 + j) * 512 + lane * 8, s_a +        (wid * 4 + j) * 512);
    gload_lds16(wsB + 8192 + (wid * 4 + j) * 512 + lane * 8, s_a + 8192 + (wid * 4 + j) * 512);
  }

  // ---- phase 1: offset conv, M=32 (27 live rows), im2col MFMA ----
  {
    f32x4 acc0 = {0.f, 0.f, 0.f, 0.f}, acc1 = {0.f, 0.f, 0.f, 0.f};
    #pragma unroll
    for (int k = 0; k < 9; ++k) {
      const int ky = k / 3, kx = k - ky * 3;
      const int y = ho + ky - 1;
      const int xx = px + kx - 1;
      const bool valid = ((unsigned)y < 64u) && ((unsigned)xx < 64u);
      const int pos = min(max(y, 0), 63) * 64 + min(max(xx, 0), 63);
      const int voff = pos * 256 + q * 16;
      #pragma unroll
      for (int c4 = 0; c4 < 4; ++c4) {
        union { uint4 u; f16x8 v; } bu;
        bu.u = *(const uint4*)(xtb + voff + c4 * 64);
        if (!valid) { bu.u.x = 0u; bu.u.y = 0u; bu.u.z = 0u; bu.u.w = 0u; }
        const int ch = k * 4 + c4;
        f16x8 a0 = *(const f16x8*)&wsA[(ch * 2    ) * 512 + lane * 8];
        f16x8 a1 = *(const f16x8*)&wsA[(ch * 2 + 1) * 512 + lane * 8];
        acc0 = __builtin_amdgcn_mfma_f32_16x16x32_f16(a0, bu.v, acc0, 0, 0, 0);
        acc1 = __builtin_amdgcn_mfma_f32_16x16x32_f16(a1, bu.v, acc1, 0, 0, 0);
      }
    }
    #pragma unroll
    for (int mt = 0; mt < 2; ++mt) {
      f32x4 a = mt ? acc1 : acc0;
      #pragma unroll
      for (int r = 0; r < 4; ++r) {
        int oc = mt * 16 + q * 4 + r;
        if (oc < 27) {
          float v = a[r] + b_off[oc];
          if (oc >= 18) v = 1.0f / (1.0f + __expf(-v));
          s_off[oc * 65 + px] = v;
        }
      }
    }
  }
  __syncthreads();   // offset row ready + S(0)/S(1) drained (vmcnt(0) at this barrier)

  // ---- phase 2: bilinear table ----
  for (int f = t; f < 576; f += 256) {
    int k = f >> 6, p = f & 63;
    int ky = k / 3, kx = k - ky * 3;
    float oy = s_off[(2 * k    ) * 65 + p];
    float ox = s_off[(2 * k + 1) * 65 + p];
    float m  = s_off[(18 + k   ) * 65 + p];
    float py  = oy + (float)(ho + ky - 1);
    float pxf = ox + (float)(p + kx - 1);
    float y0f = floorf(py), x0f = floorf(pxf);
    float wy = py - y0f, wx = pxf - x0f;
    int y0 = (int)y0f, x0 = (int)x0f;
    int y1 = y0 + 1, x1 = x0 + 1;
    bool y0v = (unsigned)y0 < 64u, y1v = (unsigned)y1 < 64u;
    bool x0v = (unsigned)x0 < 64u, x1v = (unsigned)x1 < 64u;
    int y0c = min(max(y0, 0), 63), y1c = min(max(y1, 0), 63);
    int x0c = min(max(x0, 0), 63), x1c = min(max(x1, 0), 63);
    uint4 o4;
    o4.x = (unsigned)((y0c * 64 + x0c) * 256);
    o4.y = (unsigned)((y0c * 64 + x1c) * 256);
    o4.z = (unsigned)((y1c * 64 + x0c) * 256);
    o4.w = (unsigned)((y1c * 64 + x1c) * 256);
    float4 w4;
    w4.x = (y0v && x0v) ? (1.f - wy) * (1.f - wx) * m : 0.f;
    w4.y = (y0v && x1v) ? (1.f - wy) * wx         * m : 0.f;
    w4.z = (y1v && x0v) ? wy         * (1.f - wx) * m : 0.f;
    w4.w = (y1v && x1v) ? wy         * wx         * m : 0.f;
    s_ofs[f] = o4;
    s_wt[f]  = w4;
  }
  __syncthreads();   // table ready

  // ---- phase 3: 18 half-tap iterations, counted-vmcnt pipeline ----
  f32x4 acc[8];
  #pragma unroll
  for (int mt = 0; mt < 8; ++mt) acc[mt] = (f32x4){0.f, 0.f, 0.f, 0.f};

  typedef union { uint4 u; f16x2 h[4]; } AU;
  AU Gc[8], Gn[8];

  // G(0): corners for chunks 0,1 (tap 0, c4 = 0,1)
  {
    const uint4 o4 = s_ofs[px];
    #pragma unroll
    for (int cc = 0; cc < 2; ++cc) {
      const unsigned add = q * 16 + cc * 64;
      Gc[cc * 4 + 0].u = *(const uint4*)(xtb + o4.x + add);
      Gc[cc * 4 + 1].u = *(const uint4*)(xtb + o4.y + add);
      Gc[cc * 4 + 2].u = *(const uint4*)(xtb + o4.z + add);
      Gc[cc * 4 + 3].u = *(const uint4*)(xtb + o4.w + add);
    }
  }

  #pragma unroll 2
  for (int h = 0; h < 18; ++h) {
    // counted wait: drain S(h) (and older); keep the 12 newest in flight
    if (h < 17) { asm volatile("s_waitcnt vmcnt(12)" ::: "memory"); }
    else        { asm volatile("s_waitcnt vmcnt(8)"  ::: "memory"); }
    __builtin_amdgcn_s_barrier();   // buf[h%3] now complete for ALL waves

    // issue next loads AFTER the barrier (race-freedom of the triple buffer)
    if (h < 17) {
      const int hn = h + 1;
      const int kn = hn >> 1;
      const uint4 o4 = s_ofs[kn * 64 + px];
      #pragma unroll
      for (int cc = 0; cc < 2; ++cc) {
        const unsigned add = q * 16 + (((hn << 1) + cc) & 3) * 64;
        Gn[cc * 4 + 0].u = *(const uint4*)(xtb + o4.x + add);
        Gn[cc * 4 + 1].u = *(const uint4*)(xtb + o4.y + add);
        Gn[cc * 4 + 2].u = *(const uint4*)(xtb + o4.z + add);
        Gn[cc * 4 + 3].u = *(const uint4*)(xtb + o4.w + add);
      }
    }
    if (h < 16) {
      const int hs = h + 2;
      const f16* src = wsB + hs * 8192 + (wid * 4) * 512;
      f16* dst = s_a + (hs % 3) * 8192 + (wid * 4) * 512;
      #pragma unroll
      for (int j = 0; j < 4; ++j)
        gload_lds16(src + j * 512 + lane * 8, dst + j * 512);
    }
    asm volatile("" ::: "memory");   // pin issues before compute

    // compute(h): chunks 2h, 2h+1 from buf[h%3]
    const f16* abuf = s_a + (h % 3) * 8192;
    #pragma unroll
    for (int cc = 0; cc < 2; ++cc) {
      const int ch = (h << 1) + cc;
      const float4 w4 = s_wt[(ch >> 2) * 64 + px];
      const f16 h0 = (f16)w4.x, h1 = (f16)w4.y, h2 = (f16)w4.z, h3 = (f16)w4.w;
      const f16x2 wp0 = {h0, h0}, wp1 = {h1, h1}, wp2 = {h2, h2}, wp3 = {h3, h3};
      union { f16x2 h[4]; f16x8 v; } bf;
      #pragma unroll
      for (int i = 0; i < 4; ++i) {
        f16x2 s = Gc[cc * 4 + 0].h[i] * wp0;
        s = s + Gc[cc * 4 + 1].h[i] * wp1;
        s = s + Gc[cc * 4 + 2].h[i] * wp2;
        s = s + Gc[cc * 4 + 3].h[i] * wp3;
        bf.h[i] = s;
      }
      const f16* ab = abuf + cc * 4096;
      #pragma unroll
      for (int mt = 0; mt < 8; ++mt) {
        f16x8 a = *(const f16x8*)&ab[(mt * 64 + lane) * 8];
        acc[mt] = __builtin_amdgcn_mfma_f32_16x16x32_f16(a, bf.v, acc[mt], 0, 0, 0);
      }
    }
    // rotate gather window (renamed under unroll 2)
    #pragma unroll
    for (int i = 0; i < 8; ++i) Gc[i] = Gn[i];
  }

  float* o = out + (size_t)b * 128 * 4096 + ho * 64 + px;
  #pragma unroll
  for (int mt = 0; mt < 8; ++mt) {
    #pragma unroll
    for (int r = 0; r < 4; ++r) {
      int oc = mt * 16 + q * 4 + r;
      o[oc * 4096] = acc[mt][r] + b_def[oc];
    }
  }
}

extern "C" void kernel_launch(void* const* d_in, const int* in_sizes, int n_in,
                              void* d_out, int out_size, void* d_ws, size_t ws_size,
                              hipStream_t stream) {
  const float* x     = (const float*)d_in[0];
  const float* w_off = (const float*)d_in[1];
  const float* b_off = (const float*)d_in[2];
  const float* w_def = (const float*)d_in[3];
  const float* b_def = (const float*)d_in[4];
  float* out = (float*)d_out;

  f16* wsA = (f16*)d_ws;
  f16* wsB = (f16*)((char*)d_ws + OFF_WSB);
  f16* xt  = (f16*)((char*)d_ws + OFF_XT);

  prep_transpose_kernel<<<dim3(PREP_BLOCKS + NBATCH * 64), dim3(256), 0, stream>>>(
      w_off, w_def, wsA, wsB, x, xt);
  fused_dcn_kernel<<<dim3(NBATCH * 64), dim3(256), 0, stream>>>(
      xt, wsA, wsB, b_off, b_def, out);
}